// Round 11
// baseline (29.976 us; speedup 1.0000x reference)
//
#include <hip/hip_runtime.h>
#include <hip/hip_bf16.h>
#include <math.h>

// HOG forward: im (16,3,512,512) f32 -> (16,1,31,31,2,2,9) f32
// CELL=16, BLOCK=2, NBINS=9; Hc=Wc=32, Hb=Wb=31, P=256

#define IMG_H 512
#define IMG_W 512
#define NCH 3
#define NB_ 16
#define HC 32
#define WC 32
#define HB 31
#define WB 31
#define NBINS 9

__device__ __forceinline__ int refl(int i, int n) {
    if (i < 0) i = -i;
    else if (i >= n) i = 2 * n - 2 - i;
    return i;
}

// Register-tile HOG histogram: NO LDS, NO barriers.
// Grid: 2048 blocks (16 img x 8 tile-rows x 16 tile-cols), 256 threads.
// Thread: 4 cols (float4-aligned) x 2 rows = 8 px.
// Wave = 2 cells of 32 lanes; butterfly reduce with role-split tail.
// XCD-swizzled blockIdx (bijective: 2048 % 8 == 0).
__global__ __launch_bounds__(256) void hog_hist_kernel(const float* __restrict__ im,
                                                       float* __restrict__ hist) {
    const int bid = (int)(((blockIdx.x & 7) << 8) | (blockIdx.x >> 3));
    const int b  = bid >> 7;
    const int tr = (bid >> 4) & 7;
    const int tc = bid & 15;

    const int t  = threadIdx.x;
    const int cg = t & 7;                  // col group (0..7) -> 4 cols each
    const int rg = t >> 3;                 // row group (0..31) -> 2 rows each

    const int y0 = tr * 64 + rg * 2;       // first px row of this thread
    const int x0 = tc * 32 + cg * 4;       // first px col (float4-aligned)

    const float* imb = im + (size_t)b * NCH * IMG_H * IMG_W;

    const int xl = (x0 == 0) ? 1 : x0 - 1;                  // refl(x0-1)
    const int xr = (x0 + 4 >= IMG_W) ? IMG_W - 2 : x0 + 4;  // refl(x0+4)

    // hoisted voffsets, reused across all 3 channels
    int voffC[4], voffL[4], voffR[4];
#pragma unroll
    for (int j = 0; j < 4; ++j) {
        int base = refl(y0 - 1 + j, IMG_H) * IMG_W;
        voffC[j] = base + x0;
        voffL[j] = base + xl;
        voffR[j] = base + xr;
    }

    float be[8], bgx[8], bgy[8];

#pragma unroll
    for (int c = 0; c < NCH; ++c) {
        const float* chp = imb + (size_t)c * (IMG_H * IMG_W);
        float w[4][6];
#pragma unroll
        for (int j = 0; j < 4; ++j) {
            const float4 v = *(const float4*)(chp + voffC[j]);
            w[j][0] = chp[voffL[j]];
            w[j][1] = v.x; w[j][2] = v.y; w[j][3] = v.z; w[j][4] = v.w;
            w[j][5] = chp[voffR[j]];
        }
#pragma unroll
        for (int p = 0; p < 2; ++p) {
#pragma unroll
            for (int q = 0; q < 4; ++q) {
                const int ix = p * 4 + q;
                // identical association to the verified kernel:
                float gx = ((w[p][q + 2] - w[p][q]) + 2.0f * (w[p + 1][q + 2] - w[p + 1][q]))
                         + (w[p + 2][q + 2] - w[p + 2][q]);
                float gy = ((w[p + 2][q] - w[p][q]) + 2.0f * (w[p + 2][q + 1] - w[p][q + 1]))
                         + (w[p + 2][q + 2] - w[p][q + 2]);
                float e = gx * gx + gy * gy;
                if (c == 0) {
                    be[ix] = e; bgx[ix] = gx; bgy[ix] = gy;
                } else {
                    bool gt = e > be[ix];          // branch-free cndmask x3
                    be[ix]  = gt ? e  : be[ix];
                    bgx[ix] = gt ? gx : bgx[ix];
                    bgy[ix] = gt ? gy : bgy[ix];
                }
            }
        }
    }

    // GAIN-folded minimax odd poly: tg = (9/pi)*atan(r), r in [0,1]
    const float G1  = 2.86472383f, G3 = -0.95289610f, G5 = 0.55446118f;
    const float G7  = -0.33355562f, G9 = 0.15084064f, G11 = -0.03357874f;

    float acc[NBINS];
#pragma unroll
    for (int k = 0; k < NBINS; ++k) acc[k] = 0.0f;

#pragma unroll
    for (int p = 0; p < 8; ++p) {
        float gx = bgx[p], gy = bgy[p];
        float n = __builtin_amdgcn_sqrtf(be[p]);   // raw v_sqrt, <=1 ulp
        float ax = fabsf(gx), ay = fabsf(gy);
        float mn = fminf(ax, ay), mx = fmaxf(ax, ay);
        float r  = mn * __builtin_amdgcn_rcpf(mx + 1e-37f);
        float r2 = r * r;
        float tg = r * (G1 + r2 * (G3 + r2 * (G5 + r2 * (G7 + r2 * (G9 + r2 * G11)))));
        // angle fix-ups in bin units (GAIN*pi/2 = 4.5 exact, GAIN*pi = 9 exact)
        if (ay > ax) tg = 4.5f - tg;
        if ((__float_as_uint(gx) ^ __float_as_uint(gy)) & 0x80000000u) tg = 9.0f - tg;
        float fp = tg;                     // = GAIN * (atan2(gy,gx) mod pi), [0,9]

        // tent binning with clamp folding: bin k gets n * sat(1-|fp-k|);
        // bin 0 wraps: sat(1-fp) + sat(fp-8)
        float w0 = __saturatef(1.0f - fp) + __saturatef(fp - 8.0f);
        acc[0] = fmaf(w0, n, acc[0]);
#pragma unroll
        for (int k = 1; k < NBINS; ++k) {
            float wk = __saturatef(1.0f - fabsf(fp - (float)k));
            acc[k] = fmaf(wk, n, acc[k]);
        }
    }

    // ---- butterfly reduce over each cell's 32 lanes ----
    // stages 1,2: after these, the 4 lanes of each (rg, cg-block) group hold
    // identical 9-bin partials.
#pragma unroll
    for (int k = 0; k < NBINS; ++k) acc[k] += __shfl_xor(acc[k], 1, 64);
#pragma unroll
    for (int k = 0; k < NBINS; ++k) acc[k] += __shfl_xor(acc[k], 2, 64);

    // role split: lane role m = lane&3 owns bins {m, m+4} (+ bin 8 for m==0);
    // stages 8,16,32 then run on 3 regs instead of 9. Same xor tree per bin
    // => bit-identical sums to the full 5-stage butterfly.
    const int lane = t & 63;
    const int m = lane & 3;
    float ra = (m == 0) ? acc[0] : (m == 1) ? acc[1] : (m == 2) ? acc[2] : acc[3];
    float rb = (m == 0) ? acc[4] : (m == 1) ? acc[5] : (m == 2) ? acc[6] : acc[7];
    float rc = acc[8];                     // meaningful on m==0 lanes only

    ra += __shfl_xor(ra, 8, 64);  rb += __shfl_xor(rb, 8, 64);  rc += __shfl_xor(rc, 8, 64);
    ra += __shfl_xor(ra, 16, 64); rb += __shfl_xor(rb, 16, 64); rc += __shfl_xor(rc, 16, 64);
    ra += __shfl_xor(ra, 32, 64); rb += __shfl_xor(rb, 32, 64); rc += __shfl_xor(rc, 32, 64);

    if (lane < 8) {                        // rg==0: 4 role lanes per cell
        const int cellX = tc * 2 + (lane >> 2);
        const int cellY = tr * 4 + (t >> 6);
        float* hp = hist + (((size_t)b * HC + cellY) * WC + cellX) * NBINS;
        hp[m]     = ra * (1.0f / 256.0f);
        hp[m + 4] = rb * (1.0f / 256.0f);
        if (m == 0) hp[8] = rc * (1.0f / 256.0f);
    }
}

// One WAVE per output block (4 waves / 256-thread workgroup, grid 3844).
// Lane k<36 holds value k of the 2x2x9 block; two 6-stage shfl_xor
// butterflies compute the L2 and L2-Hys norms; coalesced 36-float store.
__global__ __launch_bounds__(256) void hog_norm_kernel(const float* __restrict__ hist,
                                                       float* __restrict__ out) {
    const int t    = threadIdx.x;
    const int wv   = t >> 6;
    const int lane = t & 63;
    const int idx  = blockIdx.x * 4 + wv;      // 0..15375 (= 4*3844 exactly)

    const int b = idx / (HB * WB);
    const int r = idx - b * (HB * WB);
    const int i = r / WB;
    const int j = r - i * WB;

    float x = 0.0f;
    if (lane < 36) {
        const int cellIdx = lane / NBINS;      // 0..3
        const int bin     = lane - cellIdx * NBINS;
        const int bi = cellIdx >> 1;
        const int bj = cellIdx & 1;
        x = hist[(size_t)(((b * HC) + (i + bi)) * WC + (j + bj)) * NBINS + bin];
    }

    float ss = x * x;
#pragma unroll
    for (int mm = 1; mm <= 32; mm <<= 1) ss += __shfl_xor(ss, mm, 64);
    const float inv1 = 1.0f / (sqrtf(ss) + 1e-10f);

    const float tt = fminf(x * inv1, 0.2f);    // 0 for lanes >= 36
    float ss2 = tt * tt;
#pragma unroll
    for (int mm = 1; mm <= 32; mm <<= 1) ss2 += __shfl_xor(ss2, mm, 64);
    const float inv2 = 1.0f / (sqrtf(ss2) + 1e-10f);

    if (lane < 36) out[(size_t)idx * 36 + lane] = tt * inv2;
}

extern "C" void kernel_launch(void* const* d_in, const int* in_sizes, int n_in,
                              void* d_out, int out_size, void* d_ws, size_t ws_size,
                              hipStream_t stream) {
    const float* im = (const float*)d_in[0];
    float* out = (float*)d_out;
    float* hist = (float*)d_ws;  // 16*32*32*9 floats = 589,824 bytes

    hog_hist_kernel<<<NB_ * 8 * 16, 256, 0, stream>>>(im, hist);

    int nout_blocks = NB_ * HB * WB;           // 15376
    hog_norm_kernel<<<nout_blocks / 4, 256, 0, stream>>>(hist, out);
}

// Round 13
// 29.882 us; speedup vs baseline: 1.0032x; 1.0032x over previous
//
#include <hip/hip_runtime.h>
#include <hip/hip_bf16.h>
#include <math.h>

// HOG forward: im (16,3,512,512) f32 -> (16,1,31,31,2,2,9) f32
// CELL=16, BLOCK=2, NBINS=9; Hc=Wc=32, Hb=Wb=31, P=256

#define IMG_H 512
#define IMG_W 512
#define NCH 3
#define NB_ 16
#define HC 32
#define WC 32
#define HB 31
#define WB 31
#define NBINS 9

__device__ __forceinline__ int refl(int i, int n) {
    if (i < 0) i = -i;
    else if (i >= n) i = 2 * n - 2 - i;
    return i;
}

// Register-tile HOG histogram: NO LDS, NO barriers.
// Grid: 2048 blocks (16 img x 8 tile-rows x 16 tile-cols), 256 threads.
// Thread: 4 cols (float4-aligned) x 2 rows = 8 px.
// Wave = 2 cells of 32 lanes; butterfly reduce with role-split tail.
// XCD-swizzled blockIdx (bijective: 2048 % 8 == 0).
__global__ __launch_bounds__(256) void hog_hist_kernel(const float* __restrict__ im,
                                                       float* __restrict__ hist) {
    const int bid = (int)(((blockIdx.x & 7) << 8) | (blockIdx.x >> 3));
    const int b  = bid >> 7;
    const int tr = (bid >> 4) & 7;
    const int tc = bid & 15;

    const int t  = threadIdx.x;
    const int cg = t & 7;                  // col group (0..7) -> 4 cols each
    const int rg = t >> 3;                 // row group (0..31) -> 2 rows each

    const int y0 = tr * 64 + rg * 2;       // first px row of this thread
    const int x0 = tc * 32 + cg * 4;       // first px col (float4-aligned)

    const float* imb = im + (size_t)b * NCH * IMG_H * IMG_W;

    const int xl = (x0 == 0) ? 1 : x0 - 1;                  // refl(x0-1)
    const int xr = (x0 + 4 >= IMG_W) ? IMG_W - 2 : x0 + 4;  // refl(x0+4)

    // hoisted voffsets, reused across all 3 channels
    int voffC[4], voffL[4], voffR[4];
#pragma unroll
    for (int j = 0; j < 4; ++j) {
        int base = refl(y0 - 1 + j, IMG_H) * IMG_W;
        voffC[j] = base + x0;
        voffL[j] = base + xl;
        voffR[j] = base + xr;
    }

    float be[8], bgx[8], bgy[8];

#pragma unroll
    for (int c = 0; c < NCH; ++c) {
        const float* chp = imb + (size_t)c * (IMG_H * IMG_W);
        float w[4][6];
#pragma unroll
        for (int j = 0; j < 4; ++j) {
            const float4 v = *(const float4*)(chp + voffC[j]);
            w[j][0] = chp[voffL[j]];
            w[j][1] = v.x; w[j][2] = v.y; w[j][3] = v.z; w[j][4] = v.w;
            w[j][5] = chp[voffR[j]];
        }
#pragma unroll
        for (int p = 0; p < 2; ++p) {
#pragma unroll
            for (int q = 0; q < 4; ++q) {
                const int ix = p * 4 + q;
                // identical association to the verified kernel:
                float gx = ((w[p][q + 2] - w[p][q]) + 2.0f * (w[p + 1][q + 2] - w[p + 1][q]))
                         + (w[p + 2][q + 2] - w[p + 2][q]);
                float gy = ((w[p + 2][q] - w[p][q]) + 2.0f * (w[p + 2][q + 1] - w[p][q + 1]))
                         + (w[p + 2][q + 2] - w[p][q + 2]);
                float e = gx * gx + gy * gy;
                if (c == 0) {
                    be[ix] = e; bgx[ix] = gx; bgy[ix] = gy;
                } else {
                    bool gt = e > be[ix];          // branch-free cndmask x3
                    be[ix]  = gt ? e  : be[ix];
                    bgx[ix] = gt ? gx : bgx[ix];
                    bgy[ix] = gt ? gy : bgy[ix];
                }
            }
        }
    }

    // GAIN-folded minimax odd poly: tg = (9/pi)*atan(r), r in [0,1]
    const float G1  = 2.86472383f, G3 = -0.95289610f, G5 = 0.55446118f;
    const float G7  = -0.33355562f, G9 = 0.15084064f, G11 = -0.03357874f;

    float acc[NBINS];
#pragma unroll
    for (int k = 0; k < NBINS; ++k) acc[k] = 0.0f;

#pragma unroll
    for (int p = 0; p < 8; ++p) {
        float gx = bgx[p], gy = bgy[p];
        float n = __builtin_amdgcn_sqrtf(be[p]);   // raw v_sqrt, <=1 ulp
        float ax = fabsf(gx), ay = fabsf(gy);
        float mn = fminf(ax, ay), mx = fmaxf(ax, ay);
        float r  = mn * __builtin_amdgcn_rcpf(mx + 1e-37f);
        float r2 = r * r;
        float tg = r * (G1 + r2 * (G3 + r2 * (G5 + r2 * (G7 + r2 * (G9 + r2 * G11)))));
        // angle fix-ups in bin units (GAIN*pi/2 = 4.5 exact, GAIN*pi = 9 exact)
        if (ay > ax) tg = 4.5f - tg;
        if ((__float_as_uint(gx) ^ __float_as_uint(gy)) & 0x80000000u) tg = 9.0f - tg;
        float fp = tg;                     // = GAIN * (atan2(gy,gx) mod pi), [0,9]

        // tent binning with clamp folding: bin k gets n * sat(1-|fp-k|);
        // bin 0 wraps: sat(1-fp) + sat(fp-8)
        float w0 = __saturatef(1.0f - fp) + __saturatef(fp - 8.0f);
        acc[0] = fmaf(w0, n, acc[0]);
#pragma unroll
        for (int k = 1; k < NBINS; ++k) {
            float wk = __saturatef(1.0f - fabsf(fp - (float)k));
            acc[k] = fmaf(wk, n, acc[k]);
        }
    }

    // ---- butterfly reduce over each cell's 32 lanes ----
    // stages 1,2: after these, the 4 lanes of each (rg, cg-block) group hold
    // identical 9-bin partials.
#pragma unroll
    for (int k = 0; k < NBINS; ++k) acc[k] += __shfl_xor(acc[k], 1, 64);
#pragma unroll
    for (int k = 0; k < NBINS; ++k) acc[k] += __shfl_xor(acc[k], 2, 64);

    // role split: lane role m = lane&3 owns bins {m, m+4} (+ bin 8 for m==0);
    // stages 8,16,32 then run on 3 regs instead of 9. Same xor tree per bin
    // => bit-identical sums to the full 5-stage butterfly.
    const int lane = t & 63;
    const int m = lane & 3;
    float ra = (m == 0) ? acc[0] : (m == 1) ? acc[1] : (m == 2) ? acc[2] : acc[3];
    float rb = (m == 0) ? acc[4] : (m == 1) ? acc[5] : (m == 2) ? acc[6] : acc[7];
    float rc = acc[8];                     // meaningful on m==0 lanes only

    ra += __shfl_xor(ra, 8, 64);  rb += __shfl_xor(rb, 8, 64);  rc += __shfl_xor(rc, 8, 64);
    ra += __shfl_xor(ra, 16, 64); rb += __shfl_xor(rb, 16, 64); rc += __shfl_xor(rc, 16, 64);
    ra += __shfl_xor(ra, 32, 64); rb += __shfl_xor(rb, 32, 64); rc += __shfl_xor(rc, 32, 64);

    if (lane < 8) {                        // rg==0: 4 role lanes per cell
        const int cellX = tc * 2 + (lane >> 2);
        const int cellY = tr * 4 + (t >> 6);
        float* hp = hist + (((size_t)b * HC + cellY) * WC + cellX) * NBINS;
        hp[m]     = ra * (1.0f / 256.0f);
        hp[m + 4] = rb * (1.0f / 256.0f);
        if (m == 0) hp[8] = rc * (1.0f / 256.0f);
    }
}

// One WAVE per output block (4 waves / 256-thread workgroup, grid 3844).
// Lane k<36 holds value k of the 2x2x9 block; two 6-stage shfl_xor
// butterflies compute the L2 and L2-Hys norms; coalesced 36-float store.
__global__ __launch_bounds__(256) void hog_norm_kernel(const float* __restrict__ hist,
                                                       float* __restrict__ out) {
    const int t    = threadIdx.x;
    const int wv   = t >> 6;
    const int lane = t & 63;
    const int idx  = blockIdx.x * 4 + wv;      // 0..15375 (= 4*3844 exactly)

    const int b = idx / (HB * WB);
    const int r = idx - b * (HB * WB);
    const int i = r / WB;
    const int j = r - i * WB;

    float x = 0.0f;
    if (lane < 36) {
        const int cellIdx = lane / NBINS;      // 0..3
        const int bin     = lane - cellIdx * NBINS;
        const int bi = cellIdx >> 1;
        const int bj = cellIdx & 1;
        x = hist[(size_t)(((b * HC) + (i + bi)) * WC + (j + bj)) * NBINS + bin];
    }

    float ss = x * x;
#pragma unroll
    for (int mm = 1; mm <= 32; mm <<= 1) ss += __shfl_xor(ss, mm, 64);
    const float inv1 = 1.0f / (sqrtf(ss) + 1e-10f);

    const float tt = fminf(x * inv1, 0.2f);    // 0 for lanes >= 36
    float ss2 = tt * tt;
#pragma unroll
    for (int mm = 1; mm <= 32; mm <<= 1) ss2 += __shfl_xor(ss2, mm, 64);
    const float inv2 = 1.0f / (sqrtf(ss2) + 1e-10f);

    if (lane < 36) out[(size_t)idx * 36 + lane] = tt * inv2;
}

extern "C" void kernel_launch(void* const* d_in, const int* in_sizes, int n_in,
                              void* d_out, int out_size, void* d_ws, size_t ws_size,
                              hipStream_t stream) {
    const float* im = (const float*)d_in[0];
    float* out = (float*)d_out;
    float* hist = (float*)d_ws;  // 16*32*32*9 floats = 589,824 bytes

    hog_hist_kernel<<<NB_ * 8 * 16, 256, 0, stream>>>(im, hist);

    int nout_blocks = NB_ * HB * WB;           // 15376
    hog_norm_kernel<<<nout_blocks / 4, 256, 0, stream>>>(hist, out);
}